// Round 1
// baseline (2007.644 us; speedup 1.0000x reference)
//
#include <hip/hip_runtime.h>
#include <stdint.h>

typedef __attribute__((ext_vector_type(8))) short short8;
typedef __attribute__((ext_vector_type(4))) float f32x4;

#define B_N   512
#define NPIX  196
#define MTOT  (B_N*NPIX)     // 100352
#define NPAD  224            // padded pixel dim for adjacency GEMMs

static_assert(MTOT % 128 == 0, "M must tile by 128");

__device__ __forceinline__ float bf2f(unsigned short u){
  unsigned int x = ((unsigned int)u) << 16;
  return __builtin_bit_cast(float, x);
}
__device__ __forceinline__ unsigned short f2bf(float f){
  unsigned int x = __builtin_bit_cast(unsigned int, f);
  x += 0x7fffu + ((x >> 16) & 1u);          // RNE
  return (unsigned short)(x >> 16);
}
__device__ __forceinline__ void gload16(const void* g, void* l){
  __builtin_amdgcn_global_load_lds(
    (const __attribute__((address_space(1))) void*)(uintptr_t)g,
    (__attribute__((address_space(3))) void*)(uintptr_t)l, 16, 0, 0);
}
__device__ __forceinline__ float gelu_exact(float x){
  return 0.5f * x * (1.f + erff(x * 0.70710678118654752440f));
}

// ---------------------------------------------------------------------------
// Global-M GEMM: C[m,n] = sum_{tp,ci} A[nbr_tp(m), ci] * Bt[n, tp*256+ci]
// A: [MTOT,256] bf16 pixel-major. Bt: [NB, NTAPS*256] bf16 (pre-transposed).
// 128x128 tile, 4 waves (2x2), 16x16x32 MFMA, BK=32, global_load_lds staging.
// EPI: 0 = bias+relu -> bf16[m*256+n]
//      1 = EPI0 + also write fp32 feats NCHW
//      2 = plain -> t_cm bf16 [(b*256+n)*224 + p]   (channel-major, K-padded)
//      3 = bias -> fp32 mask scatter (ConvT tap th,tw), cols >= 80 dropped
// ---------------------------------------------------------------------------
template<int NTAPS, int EPI>
__global__ __launch_bounds__(256) void gemm_g(
    const unsigned short* __restrict__ A, const unsigned short* __restrict__ Bt,
    const unsigned short* __restrict__ zrow,
    unsigned short* __restrict__ outb, float* __restrict__ outf,
    const float* __restrict__ bias, int th, int tw)
{
  __shared__ __align__(16) char smem[16384];
  char* sA = smem; char* sB = smem + 8192;
  const int tid = threadIdx.x;
  const int wid = tid >> 6, lane = tid & 63;
  const int wr = wid >> 1, wc = wid & 1;
  const int m0 = blockIdx.x * 128, n0 = blockIdx.y * 128;
  const int rs = wid*16 + (lane >> 2);   // staged row (this lane)
  const int q  = lane & 3;               // 16B quad within a 64B LDS row
  char* dA0 = sA + wid*1024; char* dA1 = sA + 4096 + wid*1024;
  char* dB0 = sB + wid*1024; char* dB1 = sB + 4096 + wid*1024;
  const char* pB0 = (const char*)(Bt + (size_t)(n0 + rs)      * (NTAPS*256));
  const char* pB1 = (const char*)(Bt + (size_t)(n0 + rs + 64) * (NTAPS*256));

  f32x4 acc[4][4];
#pragma unroll
  for (int i=0;i<4;i++)
#pragma unroll
    for (int j=0;j<4;j++) acc[i][j] = (f32x4){0.f,0.f,0.f,0.f};

  const int m_a = m0 + rs, m_b = m0 + rs + 64;
  const int ba = m_a / NPIX, pa = m_a - ba*NPIX;
  const int bb = m_b / NPIX, pbb = m_b - bb*NPIX;
  const int ha = pa / 14, wa = pa - ha*14;
  const int hb = pbb / 14, wb = pbb - hb*14;

#pragma unroll 1
  for (int tp = 0; tp < NTAPS; ++tp) {
    const int dh = (NTAPS==9) ? (tp/3 - 1) : 0;
    const int dw = (NTAPS==9) ? (tp - (tp/3)*3 - 1) : 0;
    const int h1 = ha + dh, w1 = wa + dw;
    const int h2 = hb + dh, w2 = wb + dw;
    const char* pA0 = ((h1>=0)&(h1<14)&(w1>=0)&(w1<14))
        ? (const char*)(A + ((size_t)(ba*NPIX + h1*14 + w1)) * 256) : (const char*)zrow;
    const char* pA1 = ((h2>=0)&(h2<14)&(w2>=0)&(w2<14))
        ? (const char*)(A + ((size_t)(bb*NPIX + h2*14 + w2)) * 256) : (const char*)zrow;
    const char* pBt0 = pB0 + tp*512;
    const char* pBt1 = pB1 + tp*512;
#pragma unroll 1
    for (int kk = 0; kk < 8; ++kk) {
      const int ko = kk*64 + q*16;
      gload16(pA0 + ko, dA0);
      gload16(pA1 + ko, dA1);
      gload16(pBt0 + ko, dB0);
      gload16(pBt1 + ko, dB1);
      __syncthreads();
      short8 av[4], bv[4];
#pragma unroll
      for (int i=0;i<4;i++){
        av[i] = *(const short8*)(sA + (wr*64 + i*16 + (lane&15))*64 + (lane>>4)*16);
        bv[i] = *(const short8*)(sB + (wc*64 + i*16 + (lane&15))*64 + (lane>>4)*16);
      }
#pragma unroll
      for (int i=0;i<4;i++)
#pragma unroll
        for (int j=0;j<4;j++)
          acc[i][j] = __builtin_amdgcn_mfma_f32_16x16x32_bf16(av[i], bv[j], acc[i][j], 0,0,0);
      __syncthreads();
    }
  }

#pragma unroll
  for (int i=0;i<4;i++){
#pragma unroll
    for (int j=0;j<4;j++){
#pragma unroll
      for (int r=0;r<4;r++){
        const int row = m0 + wr*64 + i*16 + ((lane>>4)<<2) + r;
        const int col = n0 + wc*64 + j*16 + (lane&15);
        float v = acc[i][j][r];
        if constexpr (EPI == 0 || EPI == 1) {
          v += bias[col];
          v = fmaxf(v, 0.f);
          outb[(size_t)row*256 + col] = f2bf(v);
          if constexpr (EPI == 1) {
            const int b = row / NPIX, p = row - b*NPIX;
            outf[((size_t)b*256 + col)*NPIX + p] = v;
          }
        } else if constexpr (EPI == 2) {
          const int b = row / NPIX, p = row - b*NPIX;
          outb[((size_t)b*256 + col)*NPAD + p] = f2bf(v);
        } else if constexpr (EPI == 3) {
          if (col < 80) {
            const int b = row / NPIX, p = row - b*NPIX;
            const int h = p / 14, w = p - h*14;
            outf[(((size_t)b*80 + col)*28 + (2*h + th))*28 + (2*w + tw)] = v + bias[col];
          }
        }
      }
    }
  }
}

// ---------------------------------------------------------------------------
// Per-sample GEMM (adjacency & GCN aggregation), grid (2, nTiles, 512).
// A rows: b*a_rps + local (clamped); B rows: b*b_rps + local (clamped).
// EPI 4: adjacency -> bf16 A_hat[b][m][n], zero outside 196x196, skip >= 224
// EPI 5: gelu(acc + bias) -> bf16 act[(b*196+m)*256+n], rows >= 196 dropped
// ---------------------------------------------------------------------------
template<int EPI, int KI>
__global__ __launch_bounds__(256) void gemm_s(
    const unsigned short* __restrict__ Asrc, int a_rps, int a_stride, long amax,
    const unsigned short* __restrict__ Bsrc, int b_rps, int b_stride, long bmax,
    unsigned short* __restrict__ outb, const float* __restrict__ bias)
{
  __shared__ __align__(16) char smem[16384];
  char* sA = smem; char* sB = smem + 8192;
  const int tid = threadIdx.x;
  const int wid = tid >> 6, lane = tid & 63;
  const int wr = wid >> 1, wc = wid & 1;
  const int m0 = blockIdx.x * 128, n0 = blockIdx.y * 128;
  const int b  = blockIdx.z;
  const int rs = wid*16 + (lane >> 2);
  const int q  = lane & 3;
  char* dA0 = sA + wid*1024; char* dA1 = sA + 4096 + wid*1024;
  char* dB0 = sB + wid*1024; char* dB1 = sB + 4096 + wid*1024;
  long ar0 = (long)b*a_rps + m0 + rs;       if (ar0 > amax) ar0 = amax;
  long ar1 = (long)b*a_rps + m0 + rs + 64;  if (ar1 > amax) ar1 = amax;
  long br0 = (long)b*b_rps + n0 + rs;       if (br0 > bmax) br0 = bmax;
  long br1 = (long)b*b_rps + n0 + rs + 64;  if (br1 > bmax) br1 = bmax;
  const char* pA0  = (const char*)(Asrc + ar0 * a_stride);
  const char* pA1  = (const char*)(Asrc + ar1 * a_stride);
  const char* pBt0 = (const char*)(Bsrc + br0 * b_stride);
  const char* pBt1 = (const char*)(Bsrc + br1 * b_stride);

  f32x4 acc[4][4];
#pragma unroll
  for (int i=0;i<4;i++)
#pragma unroll
    for (int j=0;j<4;j++) acc[i][j] = (f32x4){0.f,0.f,0.f,0.f};

#pragma unroll 1
  for (int kk = 0; kk < KI; ++kk) {
    const int ko = kk*64 + q*16;
    gload16(pA0 + ko, dA0);
    gload16(pA1 + ko, dA1);
    gload16(pBt0 + ko, dB0);
    gload16(pBt1 + ko, dB1);
    __syncthreads();
    short8 av[4], bv[4];
#pragma unroll
    for (int i=0;i<4;i++){
      av[i] = *(const short8*)(sA + (wr*64 + i*16 + (lane&15))*64 + (lane>>4)*16);
      bv[i] = *(const short8*)(sB + (wc*64 + i*16 + (lane&15))*64 + (lane>>4)*16);
    }
#pragma unroll
    for (int i=0;i<4;i++)
#pragma unroll
      for (int j=0;j<4;j++)
        acc[i][j] = __builtin_amdgcn_mfma_f32_16x16x32_bf16(av[i], bv[j], acc[i][j], 0,0,0);
    __syncthreads();
  }

#pragma unroll
  for (int i=0;i<4;i++){
#pragma unroll
    for (int j=0;j<4;j++){
#pragma unroll
      for (int r=0;r<4;r++){
        const int ml = m0 + wr*64 + i*16 + ((lane>>4)<<2) + r;
        const int nl = n0 + wc*64 + j*16 + (lane&15);
        const float v = acc[i][j][r];
        if constexpr (EPI == 4) {
          if (ml < NPAD && nl < NPAD) {
            const float o = (ml < NPIX && nl < NPIX) ? v : 0.f;
            outb[((size_t)b*NPAD + ml)*NPAD + nl] = f2bf(o);
          }
        } else {  // EPI 5
          if (ml < NPIX) {
            const float x = v + bias[nl];
            outb[((size_t)b*NPIX + ml)*256 + nl] = f2bf(gelu_exact(x));
          }
        }
      }
    }
  }
}

// --------------------------- small kernels --------------------------------

// NCHW fp32 -> pixel-major bf16 [B*196, 256]
__global__ void k_tin(const float* __restrict__ in, unsigned short* __restrict__ out)
{
  __shared__ float t[32][29];
  const int b = blockIdx.x, p0 = blockIdx.y * 28, c0 = blockIdx.z * 32;
  const int tid = threadIdx.x;
  for (int i = tid; i < 896; i += 256) {
    const int c = i / 28, p = i - c*28;
    t[c][p] = in[((size_t)b*256 + c0 + c)*196 + p0 + p];
  }
  __syncthreads();
  for (int i = tid; i < 896; i += 256) {
    const int p = i >> 5, c = i & 31;
    out[((size_t)b*196 + p0 + p)*256 + c0 + c] = f2bf(t[c][p]);
  }
}

// row-wise L2 normalize: fn = f / max(||f||, 1e-8), one wave per row
__global__ void k_fnnorm(const unsigned short* __restrict__ f, unsigned short* __restrict__ fn)
{
  const int row  = blockIdx.x * 4 + (threadIdx.x >> 6);
  const int lane = threadIdx.x & 63;
  const unsigned short* src = f + (size_t)row*256 + lane*4;
  const float x0 = bf2f(src[0]), x1 = bf2f(src[1]), x2 = bf2f(src[2]), x3 = bf2f(src[3]);
  float s = x0*x0 + x1*x1 + x2*x2 + x3*x3;
#pragma unroll
  for (int o = 32; o > 0; o >>= 1) s += __shfl_xor(s, o, 64);
  const float scale = 1.f / fmaxf(sqrtf(s), 1e-8f);
  unsigned short* dst = fn + (size_t)row*256 + lane*4;
  dst[0]=f2bf(x0*scale); dst[1]=f2bf(x1*scale); dst[2]=f2bf(x2*scale); dst[3]=f2bf(x3*scale);
}

// d[n] = sum_m A[n,m] + 1 (A exactly symmetric -> coalesced column sum)
__global__ void k_rowsum(const unsigned short* __restrict__ Ahat, float* __restrict__ dinv)
{
  const int b = blockIdx.x, n = threadIdx.x;
  if (n >= NPAD) return;
  const unsigned short* base = Ahat + (size_t)b*NPAD*NPAD + n;
  float s = 0.f;
  for (int m = 0; m < NPAD; ++m) s += bf2f(base[(size_t)m*NPAD]);
  dinv[b*NPAD + n] = rsqrtf(fmaxf(s + 1.f, 1e-12f));
}

// A_hat[n,m] = (A[n,m] + (n==m)) * dinv[n] * dinv[m], in place
__global__ void k_anorm(unsigned short* __restrict__ Ahat, const float* __restrict__ dinv)
{
  const size_t idx = (size_t)blockIdx.x * 256 + threadIdx.x;  // 512*224*224 exactly
  const int m = (int)(idx % NPAD);
  const size_t t2 = idx / NPAD;
  const int n = (int)(t2 % NPAD);
  const int b = (int)(t2 / NPAD);
  float v = bf2f(Ahat[idx]);
  if (n == m && n < NPIX) v += 1.f;
  v *= dinv[b*NPAD + n] * dinv[b*NPAD + m];
  Ahat[idx] = f2bf(v);
}

// weight repack (bf16, B^T layouts) + zero-row + t_cm K-pad zeroing
__global__ void k_prep(const float* __restrict__ cnn_w, const float* __restrict__ up_w,
                       const float* __restrict__ gcn_w, const float* __restrict__ dec_w,
                       const float* __restrict__ pred_w,
                       unsigned short* __restrict__ bt_cnn, unsigned short* __restrict__ bt_up,
                       unsigned short* __restrict__ bt_gcn, unsigned short* __restrict__ bt_dec,
                       unsigned short* __restrict__ bt_pred, unsigned short* __restrict__ zbuf,
                       unsigned short* __restrict__ tcm)
{
  long i = (long)blockIdx.x * 256 + threadIdx.x;
  long n = 4L*256*2304;
  if (i < n) {  // Bt_cnn[l][co][(kh*3+kw)*256+ci] = cnn_w[l][co][ci][kh][kw]
    const long ci = i & 255, tp = (i >> 8) % 9, co = (i / 2304) & 255, l = i / 589824;
    bt_cnn[i] = f2bf(cnn_w[(((l*256+co)*256+ci)*3 + tp/3)*3 + (tp%3)]);
    return;
  }
  i -= n; n = 2L*256*2304;
  if (i < n) {
    const long ci = i & 255, tp = (i >> 8) % 9, co = (i / 2304) & 255, l = i / 589824;
    bt_up[i] = f2bf(up_w[(((l*256+co)*256+ci)*3 + tp/3)*3 + (tp%3)]);
    return;
  }
  i -= n; n = 2L*256*256;
  if (i < n) {  // Bt_gcn[l][co][ci] = gcn_w[l][ci][co]
    const long ci = i & 255, co = (i >> 8) & 255, l = i >> 16;
    bt_gcn[i] = f2bf(gcn_w[(l*256 + ci)*256 + co]);
    return;
  }
  i -= n; n = 4L*256*256;
  if (i < n) {  // Bt_dec[t][co][ci] = deconv_w[ci][co][t>>1][t&1]
    const long ci = i & 255, co = (i >> 8) & 255, t = i >> 16;
    bt_dec[i] = f2bf(dec_w[((ci*256 + co)*2 + (t>>1))*2 + (t&1)]);
    return;
  }
  i -= n; n = 128L*256;
  if (i < n) {  // Bt_pred[k][co], rows 80..127 zero
    const long co = i & 255, k = i >> 8;
    bt_pred[i] = (k < 80) ? f2bf(pred_w[k*256 + co]) : (unsigned short)0;
    return;
  }
  i -= n; n = 2048;
  if (i < n) { zbuf[i] = 0; return; }
  i -= n; n = 512L*256*28;
  if (i < n) {  // t_cm[b][c][196..223] = 0
    const long p = 196 + (i % 28);
    const long rest = i / 28;
    const long c = rest & 255, bb = rest >> 8;
    tcm[((size_t)(bb*256 + c))*NPAD + p] = 0;
    return;
  }
}

// ---------------------------------------------------------------------------
extern "C" void kernel_launch(void* const* d_in, const int* in_sizes, int n_in,
                              void* d_out, int out_size, void* d_ws, size_t ws_size,
                              hipStream_t stream)
{
  const float* features = (const float*)d_in[0];
  const float* cnn_w  = (const float*)d_in[1];
  const float* cnn_b  = (const float*)d_in[2];
  const float* gcn_w  = (const float*)d_in[3];
  const float* gcn_b  = (const float*)d_in[4];
  const float* up_w   = (const float*)d_in[5];
  const float* up_b   = (const float*)d_in[6];
  const float* dec_w  = (const float*)d_in[7];
  const float* dec_b  = (const float*)d_in[8];
  const float* pred_w = (const float*)d_in[9];
  const float* pred_b = (const float*)d_in[10];

  char* ws = (char*)d_ws;
  size_t o = 0;
  auto take = [&](size_t nbytes) -> char* {
    char* p = ws + o;
    o += (nbytes + 255) & ~(size_t)255;
    return p;
  };
  unsigned short* bt_cnn  = (unsigned short*)take(4L*2304*256*2);
  unsigned short* bt_up   = (unsigned short*)take(2L*2304*256*2);
  unsigned short* bt_gcn  = (unsigned short*)take(2L*256*256*2);
  unsigned short* bt_dec  = (unsigned short*)take(4L*256*256*2);
  unsigned short* bt_pred = (unsigned short*)take(128L*256*2);
  unsigned short* zbuf    = (unsigned short*)take(4096);
  unsigned short* actA    = (unsigned short*)take((size_t)MTOT*256*2);
  unsigned short* actB    = (unsigned short*)take((size_t)MTOT*256*2);
  unsigned short* ahat    = (unsigned short*)take((size_t)B_N*NPAD*NPAD*2);
  unsigned short* tcm     = (unsigned short*)take((size_t)B_N*256*NPAD*2);
  float*          dinv    = (float*)take((size_t)B_N*NPAD*4);

  float* mask  = (float*)d_out;
  float* feats = mask + (size_t)B_N*80*28*28;

  const dim3 blk(256);
  const dim3 gg(MTOT/128, 2);        // 784 x 2
  const dim3 gs(2, 2, B_N);

  k_prep<<<29832, blk, 0, stream>>>(cnn_w, up_w, gcn_w, dec_w, pred_w,
                                    bt_cnn, bt_up, bt_gcn, bt_dec, bt_pred, zbuf, tcm);
  k_tin<<<dim3(B_N, 7, 8), blk, 0, stream>>>(features, actA);

  // CNN stack (4x conv3x3+relu), ping-pong actA/actB
  gemm_g<9,0><<<gg, blk, 0, stream>>>(actA, bt_cnn + 0L*589824, zbuf, actB, nullptr, cnn_b + 0,   0,0);
  gemm_g<9,0><<<gg, blk, 0, stream>>>(actB, bt_cnn + 1L*589824, zbuf, actA, nullptr, cnn_b + 256, 0,0);
  gemm_g<9,0><<<gg, blk, 0, stream>>>(actA, bt_cnn + 2L*589824, zbuf, actB, nullptr, cnn_b + 512, 0,0);
  gemm_g<9,0><<<gg, blk, 0, stream>>>(actB, bt_cnn + 3L*589824, zbuf, actA, nullptr, cnn_b + 768, 0,0);
  // f = actA

  // cosine adjacency + sym-normalization
  k_fnnorm<<<MTOT/4, blk, 0, stream>>>(actA, actB);   // fn = actB
  gemm_s<4,8><<<gs, blk, 0, stream>>>(actB, NPIX, 256, (long)MTOT-1,
                                      actB, NPIX, 256, (long)MTOT-1, ahat, nullptr);
  k_rowsum<<<B_N, blk, 0, stream>>>(ahat, dinv);
  k_anorm<<<100352, blk, 0, stream>>>(ahat, dinv);

  // GCN layer 1: t = g @ W1 (channel-major), g1 = gelu(A_hat @ t + b1)
  gemm_g<1,2><<<gg, blk, 0, stream>>>(actA, bt_gcn, zbuf, tcm, nullptr, nullptr, 0,0);
  gemm_s<5,7><<<gs, blk, 0, stream>>>(ahat, NPAD, NPAD, (long)B_N*NPAD-1,
                                      tcm, 256, NPAD, (long)B_N*256-1, actB, gcn_b);
  // GCN layer 2
  gemm_g<1,2><<<gg, blk, 0, stream>>>(actB, bt_gcn + 65536, zbuf, tcm, nullptr, nullptr, 0,0);
  gemm_s<5,7><<<gs, blk, 0, stream>>>(ahat, NPAD, NPAD, (long)B_N*NPAD-1,
                                      tcm, 256, NPAD, (long)B_N*256-1, actA, gcn_b + 256);

  // Upsample head convs; second one also writes fp32 feats (output 1)
  gemm_g<9,0><<<gg, blk, 0, stream>>>(actA, bt_up + 0L*589824, zbuf, actB, nullptr, up_b + 0,   0,0);
  gemm_g<9,1><<<gg, blk, 0, stream>>>(actB, bt_up + 1L*589824, zbuf, actA, feats,   up_b + 256, 0,0);

  // ConvTranspose(k2,s2)+ReLU as 4 independent tap-GEMMs, fused with pred 1x1
  unsigned short* ybuf = ahat;  // A_hat no longer needed
  for (int t = 0; t < 4; ++t) {
    gemm_g<1,0><<<gg, blk, 0, stream>>>(actA, bt_dec + (long)t*65536, zbuf, ybuf, nullptr, dec_b, 0,0);
    gemm_g<1,3><<<dim3(MTOT/128, 1), blk, 0, stream>>>(ybuf, bt_pred, zbuf, nullptr, mask, pred_b, t>>1, t&1);
  }
}